// Round 1
// baseline (3337.023 us; speedup 1.0000x reference)
//
#include <hip/hip_runtime.h>

// ---------------------------------------------------------------------------
// Interaction (NequIP-style Cartesian TP message passing), MI355X fp32 baseline.
// Pipeline: CSR build -> linear_up (u = t @ W per comp) -> per-dst-node fused
// kernel: stage edges, radial MLP (8->64->64->64->704, silu), TP paths,
// register accumulate, /32, D-symmetrize, plain stores (NO atomics on output).
// ---------------------------------------------------------------------------

#define NN 8000
#define NE 256000
#define CCH 64
#define UROW 832          // 13 comps * 64 ch
#define OFF1 512000       // N*C
#define OFF2 2048000      // N*C + N*C*3

__device__ __forceinline__ float rlane(float v, int l) {
    return __int_as_float(__builtin_amdgcn_readlane(__float_as_int(v), l));
}
__device__ __forceinline__ float silu_f(float x) {
    return x / (1.f + __expf(-x));
}

// ---------------- CSR build ----------------
__global__ void k_count(const int* __restrict__ ei, int* __restrict__ counts) {
    int e = blockIdx.x * 256 + threadIdx.x;
    if (e < NE) atomicAdd(&counts[ei[NE + e]], 1);
}

__global__ __launch_bounds__(1024) void k_scan(const int* __restrict__ counts,
                                               int* __restrict__ row_ptr,
                                               int* __restrict__ cursor) {
    __shared__ int ssum[1024];
    int tid = threadIdx.x;
    int base = tid * 8;
    int v[8];
    int s = 0;
#pragma unroll
    for (int i = 0; i < 8; ++i) {
        int g = base + i;
        int x = (g < NN) ? counts[g] : 0;
        v[i] = s;
        s += x;
    }
    ssum[tid] = s;
    __syncthreads();
    for (int off = 1; off < 1024; off <<= 1) {
        int t = (tid >= off) ? ssum[tid - off] : 0;
        __syncthreads();
        ssum[tid] += t;
        __syncthreads();
    }
    int excl = ssum[tid] - s;
#pragma unroll
    for (int i = 0; i < 8; ++i) {
        int g = base + i;
        if (g < NN) {
            int val = excl + v[i];
            row_ptr[g] = val;
            cursor[g]  = val;
        }
    }
    if (tid == 0) row_ptr[NN] = NE;
}

__global__ void k_scatter(const int* __restrict__ ei, int* __restrict__ cursor,
                          int* __restrict__ sorted_eid) {
    int e = blockIdx.x * 256 + threadIdx.x;
    if (e < NE) {
        int pos = atomicAdd(&cursor[ei[NE + e]], 1);
        sorted_eid[pos] = e;
    }
}

// ---------------- linear_up: u[n][comp][c] = sum_cin t_l[n,cin,comp] W_l[cin,c]
__global__ __launch_bounds__(256) void k_linear_up(
    const float* __restrict__ t0, const float* __restrict__ t1,
    const float* __restrict__ t2, const float* __restrict__ W0,
    const float* __restrict__ W1, const float* __restrict__ W2,
    float* __restrict__ u) {
    int lane = threadIdx.x & 63;
    int n = blockIdx.x * 4 + (threadIdx.x >> 6);
    if (n >= NN) return;
    float acc[13];
#pragma unroll
    for (int i = 0; i < 13; ++i) acc[i] = 0.f;
    const float* t0r = t0 + n * 64;     // uniform across lanes -> s_load
    const float* t1r = t1 + n * 192;
    const float* t2r = t2 + n * 576;
    for (int cin = 0; cin < 64; ++cin) {
        float w0 = W0[cin * 64 + lane];
        float w1 = W1[cin * 64 + lane];
        float w2 = W2[cin * 64 + lane];
        acc[0] = fmaf(t0r[cin], w0, acc[0]);
#pragma unroll
        for (int i = 0; i < 3; ++i)
            acc[1 + i] = fmaf(t1r[cin * 3 + i], w1, acc[1 + i]);
#pragma unroll
        for (int q = 0; q < 9; ++q)
            acc[4 + q] = fmaf(t2r[cin * 9 + q], w2, acc[4 + q]);
    }
#pragma unroll
    for (int m = 0; m < 13; ++m) u[n * UROW + m * 64 + lane] = acc[m];
}

// ---------------- fused per-node main kernel ----------------
// block: 256 = 64 channels x 4 subgroups (sg). One block per destination node.
// Path split across sgs: sg0 {0,3,8}(s0), sg1 {1,4,7}(s1), sg2 {2,9,6}(s2),
// sg3 {5,10}(s1,s2)  (sg3's third slot duplicates p10, result unused).
__global__ __launch_bounds__(256) void k_main(
    const float* __restrict__ u, const int* __restrict__ row_ptr,
    const int* __restrict__ sorted_eid, const int* __restrict__ ei,
    const float* __restrict__ a0, const float* __restrict__ a1,
    const float* __restrict__ a2, const float* __restrict__ ef,
    const float* __restrict__ cut, const float* __restrict__ Wr0,
    const float* __restrict__ Wr1, const float* __restrict__ Wr2,
    const float* __restrict__ Wr3, const float* __restrict__ D0,
    const float* __restrict__ D1, const float* __restrict__ D2,
    float* __restrict__ out) {
    __shared__ float ef_l[64 * 9];      // pad 9: 2-way bank alias (free)
    __shared__ float h_a[64 * 65];      // pad 65: conflict-free reads
    __shared__ float h_b[64 * 65];
    __shared__ float a_l[64 * 13];
    __shared__ float cut_l[64];
    __shared__ int src_l[64];
    __shared__ int eid_l[64];

    int tid = threadIdx.x;
    int c = tid & 63;
    int sg = tid >> 6;
    int n = blockIdx.x;
    int beg = row_ptr[n], end = row_ptr[n + 1];
    int jb = sg * 16;

    int p0, p1, p2;
    if (sg == 0)      { p0 = 0; p1 = 3;  p2 = 8;  }
    else if (sg == 1) { p0 = 1; p1 = 4;  p2 = 7;  }
    else if (sg == 2) { p0 = 2; p1 = 9;  p2 = 6;  }
    else              { p0 = 5; p1 = 10; p2 = 10; }

    float accm[13];
#pragma unroll
    for (int i = 0; i < 13; ++i) accm[i] = 0.f;

    for (int tb = beg; tb < end; tb += 64) {
        int cnt = min(64, end - tb);
        __syncthreads();  // previous tile fully consumed
        if (tid < 64) {
            int k = tid;
            int eid = (k < cnt) ? sorted_eid[tb + k] : -1;
            eid_l[k] = eid;
            src_l[k] = (eid >= 0) ? ei[eid] : 0;
            cut_l[k] = (eid >= 0) ? cut[eid] : 0.f;
        }
        __syncthreads();
        for (int idx = tid; idx < 64 * 8; idx += 256) {
            int k = idx >> 3, r = idx & 7;
            int eid = eid_l[k];
            ef_l[k * 9 + r] = (eid >= 0) ? ef[eid * 8 + r] : 0.f;
        }
        for (int idx = tid; idx < 64 * 13; idx += 256) {
            int k = idx / 13, m = idx - k * 13;
            int eid = eid_l[k];
            float v = 0.f;
            if (eid >= 0) {
                if (m == 0)      v = a0[eid];
                else if (m < 4)  v = a1[eid * 3 + (m - 1)];
                else             v = a2[eid * 9 + (m - 4)];
            }
            a_l[k * 13 + m] = v;
        }
        __syncthreads();

        // ---- radial MLP, lanes = edge slot (padded edges have ef=0 -> h=0)
        {   // L1: ef(8) -> h1(64) in h_a
            float acc[16];
#pragma unroll
            for (int j = 0; j < 16; ++j) acc[j] = 0.f;
            for (int r = 0; r < 8; ++r) {
                float evv = ef_l[c * 9 + r];
#pragma unroll
                for (int j = 0; j < 16; ++j)
                    acc[j] = fmaf(evv, Wr0[r * 64 + jb + j], acc[j]);
            }
#pragma unroll
            for (int j = 0; j < 16; ++j) h_a[c * 65 + jb + j] = silu_f(acc[j]);
        }
        __syncthreads();
        {   // L2: h_a -> h_b
            float acc[16];
#pragma unroll
            for (int j = 0; j < 16; ++j) acc[j] = 0.f;
            for (int q = 0; q < 64; ++q) {
                float hv = h_a[c * 65 + q];
#pragma unroll
                for (int j = 0; j < 16; ++j)
                    acc[j] = fmaf(hv, Wr1[q * 64 + jb + j], acc[j]);
            }
#pragma unroll
            for (int j = 0; j < 16; ++j) h_b[c * 65 + jb + j] = silu_f(acc[j]);
        }
        __syncthreads();
        {   // L3: h_b -> h_a (= h3)
            float acc[16];
#pragma unroll
            for (int j = 0; j < 16; ++j) acc[j] = 0.f;
            for (int q = 0; q < 64; ++q) {
                float hv = h_b[c * 65 + q];
#pragma unroll
                for (int j = 0; j < 16; ++j)
                    acc[j] = fmaf(hv, Wr2[q * 64 + jb + j], acc[j]);
            }
#pragma unroll
            for (int j = 0; j < 16; ++j) h_a[c * 65 + jb + j] = silu_f(acc[j]);
        }
        __syncthreads();

        // ---- W3 + TP, 16-edge register chunks; lanes = channel c
        for (int ch = 0; ch < cnt; ch += 16) {
            int ne = min(16, cnt - ch);
            float h3t[16];  // h3[edge][c] held by lane c; readlane(.,h) = h3[edge][h]
#pragma unroll
            for (int i = 0; i < 16; ++i) h3t[i] = h_a[(ch + i) * 65 + c];
            float accw[16][3];
#pragma unroll
            for (int i = 0; i < 16; ++i) {
                accw[i][0] = 0.f; accw[i][1] = 0.f; accw[i][2] = 0.f;
            }
            for (int h = 0; h < 64; ++h) {
                const float* row = Wr3 + h * 704;
                float wv0 = row[p0 * 64 + c];
                float wv1 = row[p1 * 64 + c];
                float wv2 = row[p2 * 64 + c];
#pragma unroll
                for (int i = 0; i < 16; ++i) {
                    float hb = rlane(h3t[i], h);
                    accw[i][0] = fmaf(hb, wv0, accw[i][0]);
                    accw[i][1] = fmaf(hb, wv1, accw[i][1]);
                    accw[i][2] = fmaf(hb, wv2, accw[i][2]);
                }
            }
#pragma unroll 1
            for (int i = 0; i < 16; ++i) {
                if (i >= ne) break;
                int e = ch + i;
                float cv = cut_l[e];
                float w0 = accw[i][0] * cv;
                float w1 = accw[i][1] * cv;
                float w2 = accw[i][2] * cv;
                const float* ub = u + (size_t)src_l[e] * UROW + c;
                const float* av = a_l + e * 13;
                if (sg == 0) {            // p0, p3, p8 (use s0)
                    float s0v = ub[0];
                    accm[0] = fmaf(w0 * av[0], s0v, accm[0]);
#pragma unroll
                    for (int i3 = 0; i3 < 3; ++i3)
                        accm[1 + i3] = fmaf(w1 * av[1 + i3], s0v, accm[1 + i3]);
#pragma unroll
                    for (int q = 0; q < 9; ++q)
                        accm[4 + q] = fmaf(w2 * av[4 + q], s0v, accm[4 + q]);
                } else if (sg == 1) {     // p1, p4, p7 (use s1)
                    float s1v[3] = { ub[64], ub[128], ub[192] };
                    float d = av[1] * s1v[0] + av[2] * s1v[1] + av[3] * s1v[2];
                    accm[0] = fmaf(w0, d, accm[0]);
                    float a0v = av[0];
#pragma unroll
                    for (int i3 = 0; i3 < 3; ++i3)
                        accm[1 + i3] = fmaf(w1 * a0v, s1v[i3], accm[1 + i3]);
#pragma unroll
                    for (int i3 = 0; i3 < 3; ++i3)
#pragma unroll
                        for (int j3 = 0; j3 < 3; ++j3)
                            accm[4 + 3 * i3 + j3] =
                                fmaf(w2 * av[1 + i3], s1v[j3], accm[4 + 3 * i3 + j3]);
                } else if (sg == 2) {     // p2, p9, p6 (use s2)
                    float s2v[9];
#pragma unroll
                    for (int q = 0; q < 9; ++q) s2v[q] = ub[(4 + q) * 64];
                    float d = 0.f;
#pragma unroll
                    for (int q = 0; q < 9; ++q) d = fmaf(av[4 + q], s2v[q], d);
                    accm[0] = fmaf(w0, d, accm[0]);
                    float a0v = av[0];
#pragma unroll
                    for (int q = 0; q < 9; ++q)
                        accm[4 + q] = fmaf(w1 * a0v, s2v[q], accm[4 + q]);
#pragma unroll
                    for (int i3 = 0; i3 < 3; ++i3) {
                        float t = av[1] * s2v[3 * i3] + av[2] * s2v[3 * i3 + 1] +
                                  av[3] * s2v[3 * i3 + 2];
                        accm[1 + i3] = fmaf(w2, t, accm[1 + i3]);
                    }
                } else {                  // p5, p10 (use s1, s2)
                    float s1v[3] = { ub[64], ub[128], ub[192] };
                    float s2v[9];
#pragma unroll
                    for (int q = 0; q < 9; ++q) s2v[q] = ub[(4 + q) * 64];
#pragma unroll
                    for (int i3 = 0; i3 < 3; ++i3) {
                        float t = av[4 + 3 * i3] * s1v[0] + av[4 + 3 * i3 + 1] * s1v[1] +
                                  av[4 + 3 * i3 + 2] * s1v[2];
                        accm[1 + i3] = fmaf(w0, t, accm[1 + i3]);
                    }
#pragma unroll
                    for (int i3 = 0; i3 < 3; ++i3)
#pragma unroll
                        for (int j3 = 0; j3 < 3; ++j3) {
                            float t = av[4 + 3 * i3] * s2v[j3] +
                                      av[4 + 3 * i3 + 1] * s2v[3 + j3] +
                                      av[4 + 3 * i3 + 2] * s2v[6 + j3];
                            accm[4 + 3 * i3 + j3] = fmaf(w1, t, accm[4 + 3 * i3 + j3]);
                        }
                }
            }
        }
    }

    // ---- cross-sg reduce, /avg_neighbors, D-symmetrize, store
    __syncthreads();
    float* red = h_a;  // [4][13][64]
#pragma unroll
    for (int m = 0; m < 13; ++m) red[(sg * 13 + m) * 64 + c] = accm[m];
    __syncthreads();
    float* m_l = h_b;  // [13][64]
    for (int m = sg; m < 13; m += 4) {
        float s = red[m * 64 + c] + red[(13 + m) * 64 + c] +
                  red[(26 + m) * 64 + c] + red[(39 + m) * 64 + c];
        m_l[m * 64 + c] = s * (1.f / 32.f);
    }
    __syncthreads();
    if (sg == 0) {
        out[n * 64 + c] = m_l[c] * D0[0];
    } else if (sg == 1) {
        float v0 = m_l[64 + c], v1 = m_l[128 + c], v2 = m_l[192 + c];
#pragma unroll
        for (int j = 0; j < 3; ++j) {
            float s = v0 * D1[j] + v1 * D1[3 + j] + v2 * D1[6 + j];
            out[OFF1 + (n * 64 + c) * 3 + j] = s;
        }
    } else {
        float v[9];
#pragma unroll
        for (int p = 0; p < 9; ++p) v[p] = m_l[(4 + p) * 64 + c];
        int q0 = (sg == 2) ? 0 : 5;
        int q1 = (sg == 2) ? 5 : 9;
        for (int q = q0; q < q1; ++q) {
            float s = 0.f;
#pragma unroll
            for (int p = 0; p < 9; ++p) s = fmaf(v[p], D2[p * 9 + q], s);
            out[OFF2 + (n * 64 + c) * 9 + q] = s;
        }
    }
}

// ---------------- host launch ----------------
extern "C" void kernel_launch(void* const* d_in, const int* in_sizes, int n_in,
                              void* d_out, int out_size, void* d_ws, size_t ws_size,
                              hipStream_t stream) {
    const float* t0 = (const float*)d_in[0];
    const float* t1 = (const float*)d_in[1];
    const float* t2 = (const float*)d_in[2];
    const float* a0 = (const float*)d_in[3];
    const float* a1 = (const float*)d_in[4];
    const float* a2 = (const float*)d_in[5];
    const float* ef = (const float*)d_in[6];
    const float* cut = (const float*)d_in[7];
    const float* W0 = (const float*)d_in[8];
    const float* W1 = (const float*)d_in[9];
    const float* W2 = (const float*)d_in[10];
    const float* Wr0 = (const float*)d_in[11];
    const float* Wr1 = (const float*)d_in[12];
    const float* Wr2 = (const float*)d_in[13];
    const float* Wr3 = (const float*)d_in[14];
    const float* D0 = (const float*)d_in[15];
    const float* D1 = (const float*)d_in[16];
    const float* D2 = (const float*)d_in[17];
    const int* ei = (const int*)d_in[18];
    float* out = (float*)d_out;

    // workspace layout (floats/ints, all 4B aligned): ~27.8 MB
    float* u = (float*)d_ws;                 // 6,656,000 f
    int* counts = (int*)(u + 6656000);       // N
    int* row_ptr = counts + NN;              // N+1
    int* cursor = row_ptr + NN + 1;          // N
    int* sorted = cursor + NN;               // E

    hipMemsetAsync(counts, 0, NN * sizeof(int), stream);
    k_count<<<(NE + 255) / 256, 256, 0, stream>>>(ei, counts);
    k_scan<<<1, 1024, 0, stream>>>(counts, row_ptr, cursor);
    k_scatter<<<(NE + 255) / 256, 256, 0, stream>>>(ei, cursor, sorted);
    k_linear_up<<<NN / 4, 256, 0, stream>>>(t0, t1, t2, W0, W1, W2, u);
    k_main<<<NN, 256, 0, stream>>>(u, row_ptr, sorted, ei, a0, a1, a2, ef, cut,
                                   Wr0, Wr1, Wr2, Wr3, D0, D1, D2, out);
}

// Round 2
// 1626.744 us; speedup vs baseline: 2.0514x; 2.0514x over previous
//
#include <hip/hip_runtime.h>

// ---------------------------------------------------------------------------
// Interaction (NequIP-style Cartesian TP message passing), MI355X fp32.
// Pipeline: CSR build -> linear_up (u = t @ W per comp) -> per-dst-node fused
// kernel: stage edges, radial MLP (8->64->64->64->704, silu), TP paths,
// register accumulate, /32, D-symmetrize, plain stores (NO atomics on output).
// R2: transposed-h3 uniform ds_read_b128 broadcast (no readlane), unrolled
// epilogue (latency batching), launch_bounds(256,4).
// ---------------------------------------------------------------------------

#define NN 8000
#define NE 256000
#define CCH 64
#define UROW 832          // 13 comps * 64 ch
#define OFF1 512000       // N*C
#define OFF2 2048000      // N*C + N*C*3

__device__ __forceinline__ float silu_f(float x) {
    return x / (1.f + __expf(-x));
}

// ---------------- CSR build ----------------
__global__ void k_count(const int* __restrict__ ei, int* __restrict__ counts) {
    int e = blockIdx.x * 256 + threadIdx.x;
    if (e < NE) atomicAdd(&counts[ei[NE + e]], 1);
}

__global__ __launch_bounds__(1024) void k_scan(const int* __restrict__ counts,
                                               int* __restrict__ row_ptr,
                                               int* __restrict__ cursor) {
    __shared__ int ssum[1024];
    int tid = threadIdx.x;
    int base = tid * 8;
    int v[8];
    int s = 0;
#pragma unroll
    for (int i = 0; i < 8; ++i) {
        int g = base + i;
        int x = (g < NN) ? counts[g] : 0;
        v[i] = s;
        s += x;
    }
    ssum[tid] = s;
    __syncthreads();
    for (int off = 1; off < 1024; off <<= 1) {
        int t = (tid >= off) ? ssum[tid - off] : 0;
        __syncthreads();
        ssum[tid] += t;
        __syncthreads();
    }
    int excl = ssum[tid] - s;
#pragma unroll
    for (int i = 0; i < 8; ++i) {
        int g = base + i;
        if (g < NN) {
            int val = excl + v[i];
            row_ptr[g] = val;
            cursor[g]  = val;
        }
    }
    if (tid == 0) row_ptr[NN] = NE;
}

__global__ void k_scatter(const int* __restrict__ ei, int* __restrict__ cursor,
                          int* __restrict__ sorted_eid) {
    int e = blockIdx.x * 256 + threadIdx.x;
    if (e < NE) {
        int pos = atomicAdd(&cursor[ei[NE + e]], 1);
        sorted_eid[pos] = e;
    }
}

// ---------------- linear_up: u[n][comp][c] = sum_cin t_l[n,cin,comp] W_l[cin,c]
__global__ __launch_bounds__(256) void k_linear_up(
    const float* __restrict__ t0, const float* __restrict__ t1,
    const float* __restrict__ t2, const float* __restrict__ W0,
    const float* __restrict__ W1, const float* __restrict__ W2,
    float* __restrict__ u) {
    int lane = threadIdx.x & 63;
    int n = blockIdx.x * 4 + (threadIdx.x >> 6);
    if (n >= NN) return;
    float acc[13];
#pragma unroll
    for (int i = 0; i < 13; ++i) acc[i] = 0.f;
    const float* t0r = t0 + n * 64;
    const float* t1r = t1 + n * 192;
    const float* t2r = t2 + n * 576;
    for (int cin = 0; cin < 64; ++cin) {
        float w0 = W0[cin * 64 + lane];
        float w1 = W1[cin * 64 + lane];
        float w2 = W2[cin * 64 + lane];
        acc[0] = fmaf(t0r[cin], w0, acc[0]);
#pragma unroll
        for (int i = 0; i < 3; ++i)
            acc[1 + i] = fmaf(t1r[cin * 3 + i], w1, acc[1 + i]);
#pragma unroll
        for (int q = 0; q < 9; ++q)
            acc[4 + q] = fmaf(t2r[cin * 9 + q], w2, acc[4 + q]);
    }
#pragma unroll
    for (int m = 0; m < 13; ++m) u[n * UROW + m * 64 + lane] = acc[m];
}

// ---------------- fused per-node main kernel ----------------
// block: 256 = 64 channels x 4 subgroups (sg). One block per destination node.
// Path split across sgs: sg0 {0,3,8}(s0), sg1 {1,4,7}(s1), sg2 {2,9,6}(s2),
// sg3 {5,10}(s1,s2)  (sg3's third slot duplicates p10, result unused).
__global__ __launch_bounds__(256, 4) void k_main(
    const float* __restrict__ u, const int* __restrict__ row_ptr,
    const int* __restrict__ sorted_eid, const int* __restrict__ ei,
    const float* __restrict__ a0, const float* __restrict__ a1,
    const float* __restrict__ a2, const float* __restrict__ ef,
    const float* __restrict__ cut, const float* __restrict__ Wr0,
    const float* __restrict__ Wr1, const float* __restrict__ Wr2,
    const float* __restrict__ Wr3, const float* __restrict__ D0,
    const float* __restrict__ D1, const float* __restrict__ D2,
    float* __restrict__ out) {
    __shared__ float ef_l[64 * 9];      // stride 9: 2-way alias only (free)
    __shared__ float h_a[64 * 68];      // h1 (stride 65) then h3^T (stride 68); also reduce buf
    __shared__ float h_b[64 * 65];      // h2 (stride 65)
    __shared__ float a_l[64 * 13];
    __shared__ float cut_l[64];
    __shared__ int src_l[64];
    __shared__ int eid_l[64];

    int tid = threadIdx.x;
    int c = tid & 63;
    int sg = tid >> 6;
    int n = blockIdx.x;
    int beg = row_ptr[n], end = row_ptr[n + 1];
    int jb = sg * 16;

    int p0, p1, p2;
    if (sg == 0)      { p0 = 0; p1 = 3;  p2 = 8;  }
    else if (sg == 1) { p0 = 1; p1 = 4;  p2 = 7;  }
    else if (sg == 2) { p0 = 2; p1 = 9;  p2 = 6;  }
    else              { p0 = 5; p1 = 10; p2 = 10; }

    float accm[13];
#pragma unroll
    for (int i = 0; i < 13; ++i) accm[i] = 0.f;

    for (int tb = beg; tb < end; tb += 64) {
        int cnt = min(64, end - tb);
        __syncthreads();  // previous tile fully consumed
        if (tid < 64) {
            int k = tid;
            int eid = (k < cnt) ? sorted_eid[tb + k] : -1;
            eid_l[k] = eid;
            src_l[k] = (eid >= 0) ? ei[eid] : 0;
            cut_l[k] = (eid >= 0) ? cut[eid] : 0.f;
        }
        __syncthreads();
        for (int idx = tid; idx < 64 * 8; idx += 256) {
            int k = idx >> 3, r = idx & 7;
            int eid = eid_l[k];
            ef_l[k * 9 + r] = (eid >= 0) ? ef[eid * 8 + r] : 0.f;
        }
        for (int idx = tid; idx < 64 * 13; idx += 256) {
            int k = idx / 13, m = idx - k * 13;
            int eid = eid_l[k];
            float v = 0.f;
            if (eid >= 0) {
                if (m == 0)      v = a0[eid];
                else if (m < 4)  v = a1[eid * 3 + (m - 1)];
                else             v = a2[eid * 9 + (m - 4)];
            }
            a_l[k * 13 + m] = v;
        }
        __syncthreads();

        // ---- radial MLP, lanes = edge slot (padded edges have ef=0 -> h=0)
        {   // L1: ef(8) -> h1(64) in h_a (stride 65)
            float acc[16];
#pragma unroll
            for (int j = 0; j < 16; ++j) acc[j] = 0.f;
            for (int r = 0; r < 8; ++r) {
                float evv = ef_l[c * 9 + r];
#pragma unroll
                for (int j = 0; j < 16; ++j)
                    acc[j] = fmaf(evv, Wr0[r * 64 + jb + j], acc[j]);
            }
#pragma unroll
            for (int j = 0; j < 16; ++j) h_a[c * 65 + jb + j] = silu_f(acc[j]);
        }
        __syncthreads();
        {   // L2: h_a -> h_b
            float acc[16];
#pragma unroll
            for (int j = 0; j < 16; ++j) acc[j] = 0.f;
            for (int q = 0; q < 64; ++q) {
                float hv = h_a[c * 65 + q];
#pragma unroll
                for (int j = 0; j < 16; ++j)
                    acc[j] = fmaf(hv, Wr1[q * 64 + jb + j], acc[j]);
            }
#pragma unroll
            for (int j = 0; j < 16; ++j) h_b[c * 65 + jb + j] = silu_f(acc[j]);
        }
        __syncthreads();
        {   // L3: h_b -> h3 TRANSPOSED into h_a (h_t[h][e], stride 68)
            float acc[16];
#pragma unroll
            for (int j = 0; j < 16; ++j) acc[j] = 0.f;
            for (int q = 0; q < 64; ++q) {
                float hv = h_b[c * 65 + q];
#pragma unroll
                for (int j = 0; j < 16; ++j)
                    acc[j] = fmaf(hv, Wr2[q * 64 + jb + j], acc[j]);
            }
#pragma unroll
            for (int j = 0; j < 16; ++j) h_a[(jb + j) * 68 + c] = silu_f(acc[j]);
        }
        __syncthreads();

        // ---- W3 + TP, 16-edge register chunks; lanes = channel c
        for (int ch = 0; ch < cnt; ch += 16) {
            float accw[16][3];
#pragma unroll
            for (int i = 0; i < 16; ++i) {
                accw[i][0] = 0.f; accw[i][1] = 0.f; accw[i][2] = 0.f;
            }
#pragma unroll 2
            for (int h = 0; h < 64; ++h) {
                const float* row = Wr3 + h * 704;
                float wv0 = row[p0 * 64 + c];
                float wv1 = row[p1 * 64 + c];
                float wv2 = row[p2 * 64 + c];
                float hb[16];
                // uniform-address broadcast reads of h3^T (16B aligned rows)
                *(float4*)&hb[0]  = *(const float4*)&h_a[h * 68 + ch + 0];
                *(float4*)&hb[4]  = *(const float4*)&h_a[h * 68 + ch + 4];
                *(float4*)&hb[8]  = *(const float4*)&h_a[h * 68 + ch + 8];
                *(float4*)&hb[12] = *(const float4*)&h_a[h * 68 + ch + 12];
#pragma unroll
                for (int i = 0; i < 16; ++i) {
                    accw[i][0] = fmaf(hb[i], wv0, accw[i][0]);
                    accw[i][1] = fmaf(hb[i], wv1, accw[i][1]);
                    accw[i][2] = fmaf(hb[i], wv2, accw[i][2]);
                }
            }
            // padded slots (>= cnt): cut=0, a=0, h3=0 -> contribute exactly 0
#pragma unroll 4
            for (int i = 0; i < 16; ++i) {
                int e = ch + i;
                float cv = cut_l[e];
                float w0 = accw[i][0] * cv;
                float w1 = accw[i][1] * cv;
                float w2 = accw[i][2] * cv;
                const float* ub = u + (size_t)src_l[e] * UROW + c;
                const float* av = a_l + e * 13;
                if (sg == 0) {            // p0, p3, p8 (use s0)
                    float s0v = ub[0];
                    accm[0] = fmaf(w0 * av[0], s0v, accm[0]);
#pragma unroll
                    for (int i3 = 0; i3 < 3; ++i3)
                        accm[1 + i3] = fmaf(w1 * av[1 + i3], s0v, accm[1 + i3]);
#pragma unroll
                    for (int q = 0; q < 9; ++q)
                        accm[4 + q] = fmaf(w2 * av[4 + q], s0v, accm[4 + q]);
                } else if (sg == 1) {     // p1, p4, p7 (use s1)
                    float s1v[3] = { ub[64], ub[128], ub[192] };
                    float d = av[1] * s1v[0] + av[2] * s1v[1] + av[3] * s1v[2];
                    accm[0] = fmaf(w0, d, accm[0]);
                    float a0v = av[0];
#pragma unroll
                    for (int i3 = 0; i3 < 3; ++i3)
                        accm[1 + i3] = fmaf(w1 * a0v, s1v[i3], accm[1 + i3]);
#pragma unroll
                    for (int i3 = 0; i3 < 3; ++i3)
#pragma unroll
                        for (int j3 = 0; j3 < 3; ++j3)
                            accm[4 + 3 * i3 + j3] =
                                fmaf(w2 * av[1 + i3], s1v[j3], accm[4 + 3 * i3 + j3]);
                } else if (sg == 2) {     // p2, p9, p6 (use s2)
                    float s2v[9];
#pragma unroll
                    for (int q = 0; q < 9; ++q) s2v[q] = ub[(4 + q) * 64];
                    float d = 0.f;
#pragma unroll
                    for (int q = 0; q < 9; ++q) d = fmaf(av[4 + q], s2v[q], d);
                    accm[0] = fmaf(w0, d, accm[0]);
                    float a0v = av[0];
#pragma unroll
                    for (int q = 0; q < 9; ++q)
                        accm[4 + q] = fmaf(w1 * a0v, s2v[q], accm[4 + q]);
#pragma unroll
                    for (int i3 = 0; i3 < 3; ++i3) {
                        float t = av[1] * s2v[3 * i3] + av[2] * s2v[3 * i3 + 1] +
                                  av[3] * s2v[3 * i3 + 2];
                        accm[1 + i3] = fmaf(w2, t, accm[1 + i3]);
                    }
                } else {                  // p5, p10 (use s1, s2)
                    float s1v[3] = { ub[64], ub[128], ub[192] };
                    float s2v[9];
#pragma unroll
                    for (int q = 0; q < 9; ++q) s2v[q] = ub[(4 + q) * 64];
#pragma unroll
                    for (int i3 = 0; i3 < 3; ++i3) {
                        float t = av[4 + 3 * i3] * s1v[0] + av[4 + 3 * i3 + 1] * s1v[1] +
                                  av[4 + 3 * i3 + 2] * s1v[2];
                        accm[1 + i3] = fmaf(w0, t, accm[1 + i3]);
                    }
#pragma unroll
                    for (int i3 = 0; i3 < 3; ++i3)
#pragma unroll
                        for (int j3 = 0; j3 < 3; ++j3) {
                            float t = av[4 + 3 * i3] * s2v[j3] +
                                      av[4 + 3 * i3 + 1] * s2v[3 + j3] +
                                      av[4 + 3 * i3 + 2] * s2v[6 + j3];
                            accm[4 + 3 * i3 + j3] = fmaf(w1, t, accm[4 + 3 * i3 + j3]);
                        }
                }
            }
        }
    }

    // ---- cross-sg reduce, /avg_neighbors, D-symmetrize, store
    __syncthreads();
    float* red = h_a;  // [4][13][64] = 3328 floats <= 4352
#pragma unroll
    for (int m = 0; m < 13; ++m) red[(sg * 13 + m) * 64 + c] = accm[m];
    __syncthreads();
    float* m_l = h_b;  // [13][64]
    for (int m = sg; m < 13; m += 4) {
        float s = red[m * 64 + c] + red[(13 + m) * 64 + c] +
                  red[(26 + m) * 64 + c] + red[(39 + m) * 64 + c];
        m_l[m * 64 + c] = s * (1.f / 32.f);
    }
    __syncthreads();
    if (sg == 0) {
        out[n * 64 + c] = m_l[c] * D0[0];
    } else if (sg == 1) {
        float v0 = m_l[64 + c], v1 = m_l[128 + c], v2 = m_l[192 + c];
#pragma unroll
        for (int j = 0; j < 3; ++j) {
            float s = v0 * D1[j] + v1 * D1[3 + j] + v2 * D1[6 + j];
            out[OFF1 + (n * 64 + c) * 3 + j] = s;
        }
    } else {
        float v[9];
#pragma unroll
        for (int p = 0; p < 9; ++p) v[p] = m_l[(4 + p) * 64 + c];
        int q0 = (sg == 2) ? 0 : 5;
        int q1 = (sg == 2) ? 5 : 9;
        for (int q = q0; q < q1; ++q) {
            float s = 0.f;
#pragma unroll
            for (int p = 0; p < 9; ++p) s = fmaf(v[p], D2[p * 9 + q], s);
            out[OFF2 + (n * 64 + c) * 9 + q] = s;
        }
    }
}

// ---------------- host launch ----------------
extern "C" void kernel_launch(void* const* d_in, const int* in_sizes, int n_in,
                              void* d_out, int out_size, void* d_ws, size_t ws_size,
                              hipStream_t stream) {
    const float* t0 = (const float*)d_in[0];
    const float* t1 = (const float*)d_in[1];
    const float* t2 = (const float*)d_in[2];
    const float* a0 = (const float*)d_in[3];
    const float* a1 = (const float*)d_in[4];
    const float* a2 = (const float*)d_in[5];
    const float* ef = (const float*)d_in[6];
    const float* cut = (const float*)d_in[7];
    const float* W0 = (const float*)d_in[8];
    const float* W1 = (const float*)d_in[9];
    const float* W2 = (const float*)d_in[10];
    const float* Wr0 = (const float*)d_in[11];
    const float* Wr1 = (const float*)d_in[12];
    const float* Wr2 = (const float*)d_in[13];
    const float* Wr3 = (const float*)d_in[14];
    const float* D0 = (const float*)d_in[15];
    const float* D1 = (const float*)d_in[16];
    const float* D2 = (const float*)d_in[17];
    const int* ei = (const int*)d_in[18];
    float* out = (float*)d_out;

    // workspace layout (floats/ints, all 4B aligned): ~27.8 MB
    float* u = (float*)d_ws;                 // 6,656,000 f
    int* counts = (int*)(u + 6656000);       // N
    int* row_ptr = counts + NN;              // N+1
    int* cursor = row_ptr + NN + 1;          // N
    int* sorted = cursor + NN;               // E

    hipMemsetAsync(counts, 0, NN * sizeof(int), stream);
    k_count<<<(NE + 255) / 256, 256, 0, stream>>>(ei, counts);
    k_scan<<<1, 1024, 0, stream>>>(counts, row_ptr, cursor);
    k_scatter<<<(NE + 255) / 256, 256, 0, stream>>>(ei, cursor, sorted);
    k_linear_up<<<NN / 4, 256, 0, stream>>>(t0, t1, t2, W0, W1, W2, u);
    k_main<<<NN, 256, 0, stream>>>(u, row_ptr, sorted, ei, a0, a1, a2, ef, cut,
                                   Wr0, Wr1, Wr2, Wr3, D0, D1, D2, out);
}

// Round 3
// 1528.150 us; speedup vs baseline: 2.1837x; 1.0645x over previous
//
#include <hip/hip_runtime.h>

// ---------------------------------------------------------------------------
// Interaction (NequIP-style Cartesian TP message passing), MI355X fp32.
// Pipeline: CSR build -> linear_up (u = t @ W per comp) -> per-dst-node fused
// kernel: stage edges, radial MLP (8->64->64->64->704, silu), TP paths,
// register accumulate, /32, D-symmetrize, plain stores (NO atomics on output).
// R3: kill scratch spills — W3 chunk 16->8 (accw 48->24 regs), natural
// launch_bounds(256) (no VGPR cap), keep transposed-h3 ds_read_b128 broadcast.
// ---------------------------------------------------------------------------

#define NN 8000
#define NE 256000
#define CCH 64
#define UROW 832          // 13 comps * 64 ch
#define OFF1 512000       // N*C
#define OFF2 2048000      // N*C + N*C*3

__device__ __forceinline__ float silu_f(float x) {
    return x / (1.f + __expf(-x));
}

// ---------------- CSR build ----------------
__global__ void k_count(const int* __restrict__ ei, int* __restrict__ counts) {
    int e = blockIdx.x * 256 + threadIdx.x;
    if (e < NE) atomicAdd(&counts[ei[NE + e]], 1);
}

__global__ __launch_bounds__(1024) void k_scan(const int* __restrict__ counts,
                                               int* __restrict__ row_ptr,
                                               int* __restrict__ cursor) {
    __shared__ int ssum[1024];
    int tid = threadIdx.x;
    int base = tid * 8;
    int v[8];
    int s = 0;
#pragma unroll
    for (int i = 0; i < 8; ++i) {
        int g = base + i;
        int x = (g < NN) ? counts[g] : 0;
        v[i] = s;
        s += x;
    }
    ssum[tid] = s;
    __syncthreads();
    for (int off = 1; off < 1024; off <<= 1) {
        int t = (tid >= off) ? ssum[tid - off] : 0;
        __syncthreads();
        ssum[tid] += t;
        __syncthreads();
    }
    int excl = ssum[tid] - s;
#pragma unroll
    for (int i = 0; i < 8; ++i) {
        int g = base + i;
        if (g < NN) {
            int val = excl + v[i];
            row_ptr[g] = val;
            cursor[g]  = val;
        }
    }
    if (tid == 0) row_ptr[NN] = NE;
}

__global__ void k_scatter(const int* __restrict__ ei, int* __restrict__ cursor,
                          int* __restrict__ sorted_eid) {
    int e = blockIdx.x * 256 + threadIdx.x;
    if (e < NE) {
        int pos = atomicAdd(&cursor[ei[NE + e]], 1);
        sorted_eid[pos] = e;
    }
}

// ---------------- linear_up: u[n][comp][c] = sum_cin t_l[n,cin,comp] W_l[cin,c]
__global__ __launch_bounds__(256) void k_linear_up(
    const float* __restrict__ t0, const float* __restrict__ t1,
    const float* __restrict__ t2, const float* __restrict__ W0,
    const float* __restrict__ W1, const float* __restrict__ W2,
    float* __restrict__ u) {
    int lane = threadIdx.x & 63;
    int n = blockIdx.x * 4 + (threadIdx.x >> 6);
    if (n >= NN) return;
    float acc[13];
#pragma unroll
    for (int i = 0; i < 13; ++i) acc[i] = 0.f;
    const float* t0r = t0 + n * 64;
    const float* t1r = t1 + n * 192;
    const float* t2r = t2 + n * 576;
    for (int cin = 0; cin < 64; ++cin) {
        float w0 = W0[cin * 64 + lane];
        float w1 = W1[cin * 64 + lane];
        float w2 = W2[cin * 64 + lane];
        acc[0] = fmaf(t0r[cin], w0, acc[0]);
#pragma unroll
        for (int i = 0; i < 3; ++i)
            acc[1 + i] = fmaf(t1r[cin * 3 + i], w1, acc[1 + i]);
#pragma unroll
        for (int q = 0; q < 9; ++q)
            acc[4 + q] = fmaf(t2r[cin * 9 + q], w2, acc[4 + q]);
    }
#pragma unroll
    for (int m = 0; m < 13; ++m) u[n * UROW + m * 64 + lane] = acc[m];
}

// ---------------- fused per-node main kernel ----------------
// block: 256 = 64 channels x 4 subgroups (sg). One block per destination node.
// Path split across sgs: sg0 {0,3,8}(s0), sg1 {1,4,7}(s1), sg2 {2,9,6}(s2),
// sg3 {5,10}(s1,s2)  (sg3's third slot duplicates p10, result unused).
__global__ __launch_bounds__(256) void k_main(
    const float* __restrict__ u, const int* __restrict__ row_ptr,
    const int* __restrict__ sorted_eid, const int* __restrict__ ei,
    const float* __restrict__ a0, const float* __restrict__ a1,
    const float* __restrict__ a2, const float* __restrict__ ef,
    const float* __restrict__ cut, const float* __restrict__ Wr0,
    const float* __restrict__ Wr1, const float* __restrict__ Wr2,
    const float* __restrict__ Wr3, const float* __restrict__ D0,
    const float* __restrict__ D1, const float* __restrict__ D2,
    float* __restrict__ out) {
    __shared__ float ef_l[64 * 9];      // stride 9: 2-way alias only (free)
    __shared__ float h_a[64 * 68];      // h1 (stride 65) then h3^T (stride 68); also reduce buf
    __shared__ float h_b[64 * 65];      // h2 (stride 65)
    __shared__ float a_l[64 * 13];
    __shared__ float cut_l[64];
    __shared__ int src_l[64];
    __shared__ int eid_l[64];

    int tid = threadIdx.x;
    int c = tid & 63;
    int sg = tid >> 6;
    int n = blockIdx.x;
    int beg = row_ptr[n], end = row_ptr[n + 1];
    int jb = sg * 16;

    int p0, p1, p2;
    if (sg == 0)      { p0 = 0; p1 = 3;  p2 = 8;  }
    else if (sg == 1) { p0 = 1; p1 = 4;  p2 = 7;  }
    else if (sg == 2) { p0 = 2; p1 = 9;  p2 = 6;  }
    else              { p0 = 5; p1 = 10; p2 = 10; }

    float accm[13];
#pragma unroll
    for (int i = 0; i < 13; ++i) accm[i] = 0.f;

    for (int tb = beg; tb < end; tb += 64) {
        int cnt = min(64, end - tb);
        __syncthreads();  // previous tile fully consumed
        if (tid < 64) {
            int k = tid;
            int eid = (k < cnt) ? sorted_eid[tb + k] : -1;
            eid_l[k] = eid;
            src_l[k] = (eid >= 0) ? ei[eid] : 0;
            cut_l[k] = (eid >= 0) ? cut[eid] : 0.f;
        }
        __syncthreads();
        for (int idx = tid; idx < 64 * 8; idx += 256) {
            int k = idx >> 3, r = idx & 7;
            int eid = eid_l[k];
            ef_l[k * 9 + r] = (eid >= 0) ? ef[eid * 8 + r] : 0.f;
        }
        for (int idx = tid; idx < 64 * 13; idx += 256) {
            int k = idx / 13, m = idx - k * 13;
            int eid = eid_l[k];
            float v = 0.f;
            if (eid >= 0) {
                if (m == 0)      v = a0[eid];
                else if (m < 4)  v = a1[eid * 3 + (m - 1)];
                else             v = a2[eid * 9 + (m - 4)];
            }
            a_l[k * 13 + m] = v;
        }
        __syncthreads();

        // ---- radial MLP, lanes = edge slot (padded edges have ef=0 -> h=0)
        {   // L1: ef(8) -> h1(64) in h_a (stride 65)
            float acc[16];
#pragma unroll
            for (int j = 0; j < 16; ++j) acc[j] = 0.f;
            for (int r = 0; r < 8; ++r) {
                float evv = ef_l[c * 9 + r];
#pragma unroll
                for (int j = 0; j < 16; ++j)
                    acc[j] = fmaf(evv, Wr0[r * 64 + jb + j], acc[j]);
            }
#pragma unroll
            for (int j = 0; j < 16; ++j) h_a[c * 65 + jb + j] = silu_f(acc[j]);
        }
        __syncthreads();
        {   // L2: h_a -> h_b
            float acc[16];
#pragma unroll
            for (int j = 0; j < 16; ++j) acc[j] = 0.f;
            for (int q = 0; q < 64; ++q) {
                float hv = h_a[c * 65 + q];
#pragma unroll
                for (int j = 0; j < 16; ++j)
                    acc[j] = fmaf(hv, Wr1[q * 64 + jb + j], acc[j]);
            }
#pragma unroll
            for (int j = 0; j < 16; ++j) h_b[c * 65 + jb + j] = silu_f(acc[j]);
        }
        __syncthreads();
        {   // L3: h_b -> h3 TRANSPOSED into h_a (h_t[h][e], stride 68)
            float acc[16];
#pragma unroll
            for (int j = 0; j < 16; ++j) acc[j] = 0.f;
            for (int q = 0; q < 64; ++q) {
                float hv = h_b[c * 65 + q];
#pragma unroll
                for (int j = 0; j < 16; ++j)
                    acc[j] = fmaf(hv, Wr2[q * 64 + jb + j], acc[j]);
            }
#pragma unroll
            for (int j = 0; j < 16; ++j) h_a[(jb + j) * 68 + c] = silu_f(acc[j]);
        }
        __syncthreads();

        // ---- W3 + TP, 8-edge register chunks; lanes = channel c
        for (int ch = 0; ch < cnt; ch += 8) {
            float accw[8][3];
#pragma unroll
            for (int i = 0; i < 8; ++i) {
                accw[i][0] = 0.f; accw[i][1] = 0.f; accw[i][2] = 0.f;
            }
#pragma unroll 2
            for (int h = 0; h < 64; ++h) {
                const float* row = Wr3 + h * 704;
                float wv0 = row[p0 * 64 + c];
                float wv1 = row[p1 * 64 + c];
                float wv2 = row[p2 * 64 + c];
                float hb[8];
                // uniform-address broadcast reads of h3^T (16B aligned rows)
                *(float4*)&hb[0] = *(const float4*)&h_a[h * 68 + ch + 0];
                *(float4*)&hb[4] = *(const float4*)&h_a[h * 68 + ch + 4];
#pragma unroll
                for (int i = 0; i < 8; ++i) {
                    accw[i][0] = fmaf(hb[i], wv0, accw[i][0]);
                    accw[i][1] = fmaf(hb[i], wv1, accw[i][1]);
                    accw[i][2] = fmaf(hb[i], wv2, accw[i][2]);
                }
            }
            // padded slots (>= cnt): cut=0, a=0, h3=0 -> contribute exactly 0
#pragma unroll 4
            for (int i = 0; i < 8; ++i) {
                int e = ch + i;
                float cv = cut_l[e];
                float w0 = accw[i][0] * cv;
                float w1 = accw[i][1] * cv;
                float w2 = accw[i][2] * cv;
                const float* ub = u + (size_t)src_l[e] * UROW + c;
                const float* av = a_l + e * 13;
                if (sg == 0) {            // p0, p3, p8 (use s0)
                    float s0v = ub[0];
                    accm[0] = fmaf(w0 * av[0], s0v, accm[0]);
#pragma unroll
                    for (int i3 = 0; i3 < 3; ++i3)
                        accm[1 + i3] = fmaf(w1 * av[1 + i3], s0v, accm[1 + i3]);
#pragma unroll
                    for (int q = 0; q < 9; ++q)
                        accm[4 + q] = fmaf(w2 * av[4 + q], s0v, accm[4 + q]);
                } else if (sg == 1) {     // p1, p4, p7 (use s1)
                    float s1v[3] = { ub[64], ub[128], ub[192] };
                    float d = av[1] * s1v[0] + av[2] * s1v[1] + av[3] * s1v[2];
                    accm[0] = fmaf(w0, d, accm[0]);
                    float a0v = av[0];
#pragma unroll
                    for (int i3 = 0; i3 < 3; ++i3)
                        accm[1 + i3] = fmaf(w1 * a0v, s1v[i3], accm[1 + i3]);
#pragma unroll
                    for (int i3 = 0; i3 < 3; ++i3)
#pragma unroll
                        for (int j3 = 0; j3 < 3; ++j3)
                            accm[4 + 3 * i3 + j3] =
                                fmaf(w2 * av[1 + i3], s1v[j3], accm[4 + 3 * i3 + j3]);
                } else if (sg == 2) {     // p2, p9, p6 (use s2)
                    float s2v[9];
#pragma unroll
                    for (int q = 0; q < 9; ++q) s2v[q] = ub[(4 + q) * 64];
                    float d = 0.f;
#pragma unroll
                    for (int q = 0; q < 9; ++q) d = fmaf(av[4 + q], s2v[q], d);
                    accm[0] = fmaf(w0, d, accm[0]);
                    float a0v = av[0];
#pragma unroll
                    for (int q = 0; q < 9; ++q)
                        accm[4 + q] = fmaf(w1 * a0v, s2v[q], accm[4 + q]);
#pragma unroll
                    for (int i3 = 0; i3 < 3; ++i3) {
                        float t = av[1] * s2v[3 * i3] + av[2] * s2v[3 * i3 + 1] +
                                  av[3] * s2v[3 * i3 + 2];
                        accm[1 + i3] = fmaf(w2, t, accm[1 + i3]);
                    }
                } else {                  // p5, p10 (use s1, s2)
                    float s1v[3] = { ub[64], ub[128], ub[192] };
                    float s2v[9];
#pragma unroll
                    for (int q = 0; q < 9; ++q) s2v[q] = ub[(4 + q) * 64];
#pragma unroll
                    for (int i3 = 0; i3 < 3; ++i3) {
                        float t = av[4 + 3 * i3] * s1v[0] + av[4 + 3 * i3 + 1] * s1v[1] +
                                  av[4 + 3 * i3 + 2] * s1v[2];
                        accm[1 + i3] = fmaf(w0, t, accm[1 + i3]);
                    }
#pragma unroll
                    for (int i3 = 0; i3 < 3; ++i3)
#pragma unroll
                        for (int j3 = 0; j3 < 3; ++j3) {
                            float t = av[4 + 3 * i3] * s2v[j3] +
                                      av[4 + 3 * i3 + 1] * s2v[3 + j3] +
                                      av[4 + 3 * i3 + 2] * s2v[6 + j3];
                            accm[4 + 3 * i3 + j3] = fmaf(w1, t, accm[4 + 3 * i3 + j3]);
                        }
                }
            }
        }
    }

    // ---- cross-sg reduce, /avg_neighbors, D-symmetrize, store
    __syncthreads();
    float* red = h_a;  // [4][13][64] = 3328 floats <= 4352
#pragma unroll
    for (int m = 0; m < 13; ++m) red[(sg * 13 + m) * 64 + c] = accm[m];
    __syncthreads();
    float* m_l = h_b;  // [13][64]
    for (int m = sg; m < 13; m += 4) {
        float s = red[m * 64 + c] + red[(13 + m) * 64 + c] +
                  red[(26 + m) * 64 + c] + red[(39 + m) * 64 + c];
        m_l[m * 64 + c] = s * (1.f / 32.f);
    }
    __syncthreads();
    if (sg == 0) {
        out[n * 64 + c] = m_l[c] * D0[0];
    } else if (sg == 1) {
        float v0 = m_l[64 + c], v1 = m_l[128 + c], v2 = m_l[192 + c];
#pragma unroll
        for (int j = 0; j < 3; ++j) {
            float s = v0 * D1[j] + v1 * D1[3 + j] + v2 * D1[6 + j];
            out[OFF1 + (n * 64 + c) * 3 + j] = s;
        }
    } else {
        float v[9];
#pragma unroll
        for (int p = 0; p < 9; ++p) v[p] = m_l[(4 + p) * 64 + c];
        int q0 = (sg == 2) ? 0 : 5;
        int q1 = (sg == 2) ? 5 : 9;
        for (int q = q0; q < q1; ++q) {
            float s = 0.f;
#pragma unroll
            for (int p = 0; p < 9; ++p) s = fmaf(v[p], D2[p * 9 + q], s);
            out[OFF2 + (n * 64 + c) * 9 + q] = s;
        }
    }
}

// ---------------- host launch ----------------
extern "C" void kernel_launch(void* const* d_in, const int* in_sizes, int n_in,
                              void* d_out, int out_size, void* d_ws, size_t ws_size,
                              hipStream_t stream) {
    const float* t0 = (const float*)d_in[0];
    const float* t1 = (const float*)d_in[1];
    const float* t2 = (const float*)d_in[2];
    const float* a0 = (const float*)d_in[3];
    const float* a1 = (const float*)d_in[4];
    const float* a2 = (const float*)d_in[5];
    const float* ef = (const float*)d_in[6];
    const float* cut = (const float*)d_in[7];
    const float* W0 = (const float*)d_in[8];
    const float* W1 = (const float*)d_in[9];
    const float* W2 = (const float*)d_in[10];
    const float* Wr0 = (const float*)d_in[11];
    const float* Wr1 = (const float*)d_in[12];
    const float* Wr2 = (const float*)d_in[13];
    const float* Wr3 = (const float*)d_in[14];
    const float* D0 = (const float*)d_in[15];
    const float* D1 = (const float*)d_in[16];
    const float* D2 = (const float*)d_in[17];
    const int* ei = (const int*)d_in[18];
    float* out = (float*)d_out;

    // workspace layout (floats/ints, all 4B aligned): ~27.8 MB
    float* u = (float*)d_ws;                 // 6,656,000 f
    int* counts = (int*)(u + 6656000);       // N
    int* row_ptr = counts + NN;              // N+1
    int* cursor = row_ptr + NN + 1;          // N
    int* sorted = cursor + NN;               // E

    hipMemsetAsync(counts, 0, NN * sizeof(int), stream);
    k_count<<<(NE + 255) / 256, 256, 0, stream>>>(ei, counts);
    k_scan<<<1, 1024, 0, stream>>>(counts, row_ptr, cursor);
    k_scatter<<<(NE + 255) / 256, 256, 0, stream>>>(ei, cursor, sorted);
    k_linear_up<<<NN / 4, 256, 0, stream>>>(t0, t1, t2, W0, W1, W2, u);
    k_main<<<NN, 256, 0, stream>>>(u, row_ptr, sorted, ei, a0, a1, a2, ef, cut,
                                   Wr0, Wr1, Wr2, Wr3, D0, D1, D2, out);
}